// Round 10
// baseline (99.107 us; speedup 1.0000x reference)
//
#include <hip/hip_runtime.h>
#include <math.h>

// Problem: B=64, N=1568, D=768, groups=8, rows/group=196, T=1568.
// Output (B, 393, 768) f32 = [cls row | 196 rows of group i0 | 196 rows of group i1].
//
// Reduction: top_k ranking depends only on t[b,g] = xn[b,g] . u,
// u = w1 @ (w2 @ (w3@w4)[0:384]).  (x_a term constant per batch; min-max
// normalization monotone.)  Output is then a pure gather of inp rows.
//
// Structure (4 graph nodes):
//   memset(8B counters) -> k_gemv_chain (64 blocks, 2 internal barriers)
//                       -> k_max_score (512 blocks) -> k_gather (512 blocks)
//
// LESSONS (r6-r8): fusing the streaming kernels via agent-scope spin-waits
// regressed +40us — per-iteration ACQUIRE polls issue L2 invalidations that
// destroy concurrent streaming bandwidth. The GEMV chain runs ALONE, so its
// barriers are safe; they use RELAXED polls + one fence per barrier.

typedef float f32x4 __attribute__((ext_vector_type(4)));
typedef float f32x2 __attribute__((ext_vector_type(2)));

#define SCOPE_AGENT __HIP_MEMORY_SCOPE_AGENT

// ---------------- kernel 1: fused GEMV chain v -> p -> u ----------------
// 64 blocks x 256 threads (256 waves total; trivially co-resident).
// bar[0..1] zeroed by the preceding 8-byte memset each call.
// Barrier: release-fence once, relaxed add, relaxed polls, acquire-fence once.
__global__ __launch_bounds__(256) void k_gemv_chain(
    const float* __restrict__ w3, const float* __restrict__ w4,
    const float* __restrict__ w2, const float* __restrict__ w1,
    float* __restrict__ v, float* __restrict__ p, float* __restrict__ u,
    int* __restrict__ bar)
{
    const int tid = threadIdx.x;
    const int gw = blockIdx.x * 4 + (tid >> 6);   // global wave 0..255
    const int lane = tid & 63;

    // ---- stage 1: v[r] = w3[r, 0:768] . w4, r in [0, 384) ----
    {
        const f32x4* b4 = reinterpret_cast<const f32x4*>(w4);
        for (int r = gw; r < 384; r += 256) {
            const f32x4* a4 = reinterpret_cast<const f32x4*>(w3 + (size_t)r * 768);
            float s = 0.f;
#pragma unroll
            for (int i = 0; i < 3; ++i) {
                f32x4 a = a4[lane + 64 * i];
                f32x4 b = b4[lane + 64 * i];
                s += a.x * b.x + a.y * b.y + a.z * b.z + a.w * b.w;
            }
#pragma unroll
            for (int off = 32; off; off >>= 1) s += __shfl_down(s, off);
            if (lane == 0) v[r] = s;
        }
    }
    __syncthreads();
    if (tid == 0) {
        __builtin_amdgcn_fence(__ATOMIC_RELEASE, "agent");
        __hip_atomic_fetch_add(&bar[0], 1, __ATOMIC_RELAXED, SCOPE_AGENT);
        while (__hip_atomic_load(&bar[0], __ATOMIC_RELAXED, SCOPE_AGENT) < 64)
            __builtin_amdgcn_s_sleep(2);
        __builtin_amdgcn_fence(__ATOMIC_ACQUIRE, "agent");
    }
    __syncthreads();

    // ---- stage 2: p[r] = w2[r, 0:384] . v, r in [0, 768) ----
    {
        const f32x2* b2 = reinterpret_cast<const f32x2*>(v);
        for (int r = gw; r < 768; r += 256) {
            const f32x2* a2 = reinterpret_cast<const f32x2*>(w2 + (size_t)r * 384);
            float s = 0.f;
#pragma unroll
            for (int i = 0; i < 3; ++i) {
                f32x2 a = a2[lane + 64 * i];
                f32x2 b = b2[lane + 64 * i];
                s += a.x * b.x + a.y * b.y;
            }
#pragma unroll
            for (int off = 32; off; off >>= 1) s += __shfl_down(s, off);
            if (lane == 0) p[r] = s;
        }
    }
    __syncthreads();
    if (tid == 0) {
        __builtin_amdgcn_fence(__ATOMIC_RELEASE, "agent");
        __hip_atomic_fetch_add(&bar[1], 1, __ATOMIC_RELAXED, SCOPE_AGENT);
        while (__hip_atomic_load(&bar[1], __ATOMIC_RELAXED, SCOPE_AGENT) < 64)
            __builtin_amdgcn_s_sleep(2);
        __builtin_amdgcn_fence(__ATOMIC_ACQUIRE, "agent");
    }
    __syncthreads();

    // ---- stage 3: u[r] = w1[r, 0:768] . p, r in [0, 768) ----
    {
        const f32x4* b4 = reinterpret_cast<const f32x4*>(p);
        for (int r = gw; r < 768; r += 256) {
            const f32x4* a4 = reinterpret_cast<const f32x4*>(w1 + (size_t)r * 768);
            float s = 0.f;
#pragma unroll
            for (int i = 0; i < 3; ++i) {
                f32x4 a = a4[lane + 64 * i];
                f32x4 b = b4[lane + 64 * i];
                s += a.x * b.x + a.y * b.y + a.z * b.z + a.w * b.w;
            }
#pragma unroll
            for (int off = 32; off; off >>= 1) s += __shfl_down(s, off);
            if (lane == 0) u[r] = s;
        }
    }
}

// ---------------- fused max-over-rows + layernorm + score ----------------
// One block per (b,g).  768 threads: col = tid%192 (float4 lane), chunk = tid/192
// handles 49 of the 196 rows.  Single fused 5-value reduction -> t[b*8+g].
//   t = rstd*(S2 - mu*S3) + S4, with S = Σ_d (xm, xm^2, xm*lw*u, lw*u, lb*u).
__global__ __launch_bounds__(768) void k_max_score(const float* __restrict__ x,
                                                   const float* __restrict__ ln_w,
                                                   const float* __restrict__ ln_b,
                                                   const float* __restrict__ u,
                                                   float* __restrict__ t_out) {
    const int bg = blockIdx.x;            // 0..511
    const int b = bg >> 3;
    const int g = bg & 7;
    const int tid = threadIdx.x;          // 0..767
    const int col = tid % 192;            // float4 column
    const int chunk = tid / 192;          // 0..3, 49 rows each

    // hoist parameter loads above the streaming loop
    const float lw = ln_w[tid];
    const float lb = ln_b[tid];
    const float ud = u[tid];

    const f32x4* base = reinterpret_cast<const f32x4*>(
        x + ((size_t)b * 1568 + (size_t)g * 196 + (size_t)chunk * 49) * 768) + col;

    f32x4 mx = {-INFINITY, -INFINITY, -INFINITY, -INFINITY};
#pragma unroll 7
    for (int r = 0; r < 49; ++r) {
        f32x4 vv = __builtin_nontemporal_load(base + (size_t)r * 192);
        mx.x = fmaxf(mx.x, vv.x);
        mx.y = fmaxf(mx.y, vv.y);
        mx.z = fmaxf(mx.z, vv.z);
        mx.w = fmaxf(mx.w, vv.w);
    }

    __shared__ f32x4 sm4[4][192];         // 12 KiB
    __shared__ float red[12][5];

    sm4[chunk][col] = mx;
    __syncthreads();

    // each thread owns ONE d element of the combined max
    const float* smf = reinterpret_cast<const float*>(sm4);
    const float xmd = fmaxf(fmaxf(smf[0 * 768 + tid], smf[1 * 768 + tid]),
                            fmaxf(smf[2 * 768 + tid], smf[3 * 768 + tid]));

    // fused 5-value reduction: Σxm, Σxm², Σxm·lw·u, Σlw·u, Σlb·u
    const float lu = lw * ud;
    float a0 = xmd, a1 = xmd * xmd, a2 = xmd * lu, a3 = lu, a4 = lb * ud;
#pragma unroll
    for (int off = 32; off; off >>= 1) {
        a0 += __shfl_down(a0, off);
        a1 += __shfl_down(a1, off);
        a2 += __shfl_down(a2, off);
        a3 += __shfl_down(a3, off);
        a4 += __shfl_down(a4, off);
    }
    const int wave = tid >> 6;
    if ((tid & 63) == 0) {
        red[wave][0] = a0; red[wave][1] = a1; red[wave][2] = a2;
        red[wave][3] = a3; red[wave][4] = a4;
    }
    __syncthreads();
    if (tid == 0) {
        float S0 = 0.f, S1 = 0.f, S2 = 0.f, S3 = 0.f, S4 = 0.f;
#pragma unroll
        for (int w = 0; w < 12; ++w) {
            S0 += red[w][0]; S1 += red[w][1]; S2 += red[w][2];
            S3 += red[w][3]; S4 += red[w][4];
        }
        const float mu   = S0 * (1.0f / 768.0f);
        const float var  = S1 * (1.0f / 768.0f) - mu * mu;
        const float rstd = 1.0f / sqrtf(var + 768.0f);   // EPS = 768.0
        t_out[bg] = rstd * (S2 - mu * S3) + S4;
    }
}

// ---------------- top-2 select + gather ----------------
// grid (64, 8); block = 768 threads.  Block (b, chunk) copies rows
// [chunk*50, min(chunk*50+50, 393)).  Top-2 computed once, LDS broadcast.
// Load->store software-pipelined (one extra row load in flight).
__global__ __launch_bounds__(768) void k_gather(const float* __restrict__ inp,
                                                const float* __restrict__ t,
                                                float* __restrict__ out) {
    const int b = blockIdx.x;             // 0..63
    const int chunk = blockIdx.y;         // 0..7
    const int base = chunk * 50;
    const int nrows = min(50, 393 - base);
    const int tid = threadIdx.x;
    const int col = tid % 192;            // float4 column
    const int rsub = tid / 192;           // 0..3

    __shared__ int sIdx[2];
    if (tid == 0) {
        // top-2 of 8 scores; jax.lax.top_k tie-break = lower index first
        const float* tb = t + b * 8;
        float best = tb[0];
        int i0 = 0;
#pragma unroll
        for (int gi = 1; gi < 8; ++gi) {
            const float v = tb[gi];
            if (v > best) { best = v; i0 = gi; }
        }
        float best2 = -INFINITY;
        int i1 = 0;
#pragma unroll
        for (int gi = 0; gi < 8; ++gi) {
            if (gi == i0) continue;
            const float v = tb[gi];
            if (v > best2) { best2 = v; i1 = gi; }
        }
        sIdx[0] = i0;
        sIdx[1] = i1;
    }
    __syncthreads();
    const int i0 = sIdx[0], i1 = sIdx[1];

    const f32x4* src_b = reinterpret_cast<const f32x4*>(inp) + (size_t)b * 1569 * 192;
    f32x4* dst_b = reinterpret_cast<f32x4*>(out) + (size_t)b * 393 * 192;

    auto src_of = [&](int it) -> const f32x4* {
        const int row = base + rsub + 4 * it;
        int src_row;
        if (row == 0) {
            src_row = 0;                  // cls token
        } else {
            const int q = row - 1;        // 0..391
            const int gsel = (q < 196) ? i0 : i1;
            const int r = (q < 196) ? q : q - 196;
            src_row = 1 + gsel * 196 + r;
        }
        return src_b + (size_t)src_row * 192 + col;
    };

    const int nit = (nrows - rsub + 3) >> 2;   // rows handled by this thread
    f32x4 cur = __builtin_nontemporal_load(src_of(0));
    for (int it = 0; it < nit; ++it) {
        f32x4 nxt;
        if (it + 1 < nit) nxt = __builtin_nontemporal_load(src_of(it + 1));
        const int row = base + rsub + 4 * it;
        __builtin_nontemporal_store(cur, dst_b + (size_t)row * 192 + col);
        cur = nxt;
    }
}

extern "C" void kernel_launch(void* const* d_in, const int* in_sizes, int n_in,
                              void* d_out, int out_size, void* d_ws, size_t ws_size,
                              hipStream_t stream) {
    const float* x    = (const float*)d_in[0];
    const float* inp  = (const float*)d_in[1];
    const float* ln_w = (const float*)d_in[2];
    const float* ln_b = (const float*)d_in[3];
    const float* w1   = (const float*)d_in[4];
    const float* w2   = (const float*)d_in[5];
    const float* w3   = (const float*)d_in[6];
    const float* w4   = (const float*)d_in[7];
    float* out = (float*)d_out;

    float* ws = (float*)d_ws;
    float* v = ws;            // 384 f32 used (only v_top feeds w2)
    float* p = ws + 768;      // 768 f32
    float* u = ws + 1536;     // 768 f32
    float* t = ws + 2304;     // 512 f32  (all fully written before read)
    int* bar = (int*)(ws + 2816);    // bar[0..1]

    // zero the chain's barrier counters (8 bytes; capturable, deterministic)
    hipMemsetAsync(bar, 0, 2 * sizeof(int), stream);

    k_gemv_chain<<<dim3(64), dim3(256), 0, stream>>>(w3, w4, w2, w1, v, p, u, bar);
    k_max_score<<<dim3(512), dim3(768), 0, stream>>>(x, ln_w, ln_b, u, t);
    k_gather  <<<dim3(64, 8), dim3(768), 0, stream>>>(inp, t, out);
}

// Round 11
// 90.241 us; speedup vs baseline: 1.0982x; 1.0982x over previous
//
#include <hip/hip_runtime.h>
#include <hip/hip_bf16.h>
#include <math.h>

// Problem: B=64, N=1568, D=768, groups=8, rows/group=196, T=1568.
// Output (B, 393, 768) f32 = [cls row | 196 rows of group idx0 | 196 rows of group idx1].
//
// Reduction: top_k ranking depends only on t[b,g] = xn[b,g] . u,
// u = w1 @ (w2 @ (w3@w4)[0:384]).  (x_a term constant per batch; min-max
// normalization monotone.)  Output is then a pure gather of inp rows.
//
// Epilogue algebra (single reduction round):
//   t = rstd*(S2 - mu*S3) + S4, with S = Σ_d (xm, xm^2, xm*lw*u, lw*u, lb*u).
//
// LESSONS (r6-r9, measured): device-side cross-workgroup barriers lose to
// serial launches on gfx950 graph-replay — r6/r7 fused stream+gather via
// agent-scope spin-waits: +40us (acquire polls invalidate L2 under streaming);
// r9 GEMV chain with relaxed polls + single fences, running ALONE: still
// +8.6us vs three plain launches. Serial 5-node structure is fastest known.
// Also r6: __launch_bounds__(768,6) VGPR-capped the streaming loop (spills).
//
// Ceilings (measured): max_score ~6.5 TB/s pure-read, gather ~5.9 TB/s mixed
// — both at the achievable HBM ceilings; remaining ~14us is launch latency.

typedef float f32x4 __attribute__((ext_vector_type(4)));
typedef float f32x2 __attribute__((ext_vector_type(2)));

// ---------------- GEMV kernels (one wave per row, 4 rows/block) ----------------
// rows of length 768 (used for v = w3@w4 [384 rows] and u = w1@p [768 rows])
__global__ __launch_bounds__(256) void k_gemv768(const float* __restrict__ M,
                                                 const float* __restrict__ vec,
                                                 float* __restrict__ outv) {
    const int wave = threadIdx.x >> 6;
    const int lane = threadIdx.x & 63;
    const int row = blockIdx.x * 4 + wave;
    const f32x4* r4 = reinterpret_cast<const f32x4*>(M + (size_t)row * 768);
    const f32x4* v4 = reinterpret_cast<const f32x4*>(vec);
    float s = 0.f;
#pragma unroll
    for (int i = 0; i < 3; ++i) {
        f32x4 a = r4[lane + 64 * i];
        f32x4 b = v4[lane + 64 * i];
        s += a.x * b.x + a.y * b.y + a.z * b.z + a.w * b.w;
    }
#pragma unroll
    for (int off = 32; off; off >>= 1) s += __shfl_down(s, off);
    if (lane == 0) outv[row] = s;
}

// rows of length 384 (p = w2 @ v_top, 768 rows)
__global__ __launch_bounds__(256) void k_gemv384(const float* __restrict__ M,
                                                 const float* __restrict__ vec,
                                                 float* __restrict__ outv) {
    const int wave = threadIdx.x >> 6;
    const int lane = threadIdx.x & 63;
    const int row = blockIdx.x * 4 + wave;
    const f32x2* r2 = reinterpret_cast<const f32x2*>(M + (size_t)row * 384);
    const f32x2* v2 = reinterpret_cast<const f32x2*>(vec);
    float s = 0.f;
#pragma unroll
    for (int i = 0; i < 3; ++i) {
        f32x2 a = r2[lane + 64 * i];
        f32x2 b = v2[lane + 64 * i];
        s += a.x * b.x + a.y * b.y;
    }
#pragma unroll
    for (int off = 32; off; off >>= 1) s += __shfl_down(s, off);
    if (lane == 0) outv[row] = s;
}

// ---------------- fused max-over-rows + layernorm + score ----------------
// One block per (b,g).  768 threads: col = tid%192 (float4 lane), chunk = tid/192
// handles 49 of the 196 rows.  Single fused 5-value reduction -> t[b*8+g].
__global__ __launch_bounds__(768) void k_max_score(const float* __restrict__ x,
                                                   const float* __restrict__ ln_w,
                                                   const float* __restrict__ ln_b,
                                                   const float* __restrict__ u,
                                                   float* __restrict__ t_out) {
    const int bg = blockIdx.x;            // 0..511
    const int b = bg >> 3;
    const int g = bg & 7;
    const int tid = threadIdx.x;          // 0..767
    const int col = tid % 192;            // float4 column
    const int chunk = tid / 192;          // 0..3, 49 rows each

    // hoist parameter loads above the streaming loop
    const float lw = ln_w[tid];
    const float lb = ln_b[tid];
    const float ud = u[tid];

    const f32x4* base = reinterpret_cast<const f32x4*>(
        x + ((size_t)b * 1568 + (size_t)g * 196 + (size_t)chunk * 49) * 768) + col;

    f32x4 mx = {-INFINITY, -INFINITY, -INFINITY, -INFINITY};
#pragma unroll 7
    for (int r = 0; r < 49; ++r) {
        f32x4 vv = __builtin_nontemporal_load(base + (size_t)r * 192);
        mx.x = fmaxf(mx.x, vv.x);
        mx.y = fmaxf(mx.y, vv.y);
        mx.z = fmaxf(mx.z, vv.z);
        mx.w = fmaxf(mx.w, vv.w);
    }

    __shared__ f32x4 sm4[4][192];         // 12 KiB
    __shared__ float red[12][5];

    sm4[chunk][col] = mx;
    __syncthreads();

    // each thread owns ONE d element of the combined max
    const float* smf = reinterpret_cast<const float*>(sm4);
    const float xmd = fmaxf(fmaxf(smf[0 * 768 + tid], smf[1 * 768 + tid]),
                            fmaxf(smf[2 * 768 + tid], smf[3 * 768 + tid]));

    // fused 5-value reduction: Σxm, Σxm², Σxm·lw·u, Σlw·u, Σlb·u
    const float lu = lw * ud;
    float a0 = xmd, a1 = xmd * xmd, a2 = xmd * lu, a3 = lu, a4 = lb * ud;
#pragma unroll
    for (int off = 32; off; off >>= 1) {
        a0 += __shfl_down(a0, off);
        a1 += __shfl_down(a1, off);
        a2 += __shfl_down(a2, off);
        a3 += __shfl_down(a3, off);
        a4 += __shfl_down(a4, off);
    }
    const int wave = tid >> 6;
    if ((tid & 63) == 0) {
        red[wave][0] = a0; red[wave][1] = a1; red[wave][2] = a2;
        red[wave][3] = a3; red[wave][4] = a4;
    }
    __syncthreads();
    if (tid == 0) {
        float S0 = 0.f, S1 = 0.f, S2 = 0.f, S3 = 0.f, S4 = 0.f;
#pragma unroll
        for (int w = 0; w < 12; ++w) {
            S0 += red[w][0]; S1 += red[w][1]; S2 += red[w][2];
            S3 += red[w][3]; S4 += red[w][4];
        }
        const float mu   = S0 * (1.0f / 768.0f);
        const float var  = S1 * (1.0f / 768.0f) - mu * mu;
        const float rstd = 1.0f / sqrtf(var + 768.0f);   // EPS = 768.0
        t_out[bg] = rstd * (S2 - mu * S3) + S4;
    }
}

// ---------------- top-2 select + gather ----------------
// grid (64, 8); block = 768 threads.  Block (b, chunk) copies rows
// [chunk*50, min(chunk*50+50, 393)).  Top-2 computed once, LDS broadcast.
// Load->store software-pipelined (one extra row load in flight).
__global__ __launch_bounds__(768) void k_gather(const float* __restrict__ inp,
                                                const float* __restrict__ t,
                                                float* __restrict__ out) {
    const int b = blockIdx.x;             // 0..63
    const int chunk = blockIdx.y;         // 0..7
    const int base = chunk * 50;
    const int nrows = min(50, 393 - base);
    const int tid = threadIdx.x;
    const int col = tid % 192;            // float4 column
    const int rsub = tid / 192;           // 0..3

    __shared__ int sIdx[2];
    if (tid == 0) {
        // top-2 of 8 scores; jax.lax.top_k tie-break = lower index first
        const float* tb = t + b * 8;
        float best = tb[0];
        int i0 = 0;
#pragma unroll
        for (int gi = 1; gi < 8; ++gi) {
            const float v = tb[gi];
            if (v > best) { best = v; i0 = gi; }
        }
        float best2 = -INFINITY;
        int i1 = 0;
#pragma unroll
        for (int gi = 0; gi < 8; ++gi) {
            if (gi == i0) continue;
            const float v = tb[gi];
            if (v > best2) { best2 = v; i1 = gi; }
        }
        sIdx[0] = i0;
        sIdx[1] = i1;
    }
    __syncthreads();
    const int i0 = sIdx[0], i1 = sIdx[1];

    const f32x4* src_b = reinterpret_cast<const f32x4*>(inp) + (size_t)b * 1569 * 192;
    f32x4* dst_b = reinterpret_cast<f32x4*>(out) + (size_t)b * 393 * 192;

    auto src_of = [&](int it) -> const f32x4* {
        const int row = base + rsub + 4 * it;
        int src_row;
        if (row == 0) {
            src_row = 0;                  // cls token
        } else {
            const int q = row - 1;        // 0..391
            const int gsel = (q < 196) ? i0 : i1;
            const int r = (q < 196) ? q : q - 196;
            src_row = 1 + gsel * 196 + r;
        }
        return src_b + (size_t)src_row * 192 + col;
    };

    const int nit = (nrows - rsub + 3) >> 2;   // rows handled by this thread
    f32x4 cur = __builtin_nontemporal_load(src_of(0));
    for (int it = 0; it < nit; ++it) {
        f32x4 nxt;
        if (it + 1 < nit) nxt = __builtin_nontemporal_load(src_of(it + 1));
        const int row = base + rsub + 4 * it;
        __builtin_nontemporal_store(cur, dst_b + (size_t)row * 192 + col);
        cur = nxt;
    }
}

extern "C" void kernel_launch(void* const* d_in, const int* in_sizes, int n_in,
                              void* d_out, int out_size, void* d_ws, size_t ws_size,
                              hipStream_t stream) {
    const float* x    = (const float*)d_in[0];
    const float* inp  = (const float*)d_in[1];
    const float* ln_w = (const float*)d_in[2];
    const float* ln_b = (const float*)d_in[3];
    const float* w1   = (const float*)d_in[4];
    const float* w2   = (const float*)d_in[5];
    const float* w3   = (const float*)d_in[6];
    const float* w4   = (const float*)d_in[7];
    float* out = (float*)d_out;

    float* ws = (float*)d_ws;
    float* v = ws;            // 384 f32 used (only v_top feeds w2)
    float* p = ws + 768;      // 768 f32
    float* u = ws + 1536;     // 768 f32
    float* t = ws + 2304;     // 512 f32  (all fully written before read)

    k_gemv768<<<dim3( 96), dim3(256), 0, stream>>>(w3, w4, v);   // v[0:384]
    k_gemv384<<<dim3(192), dim3(256), 0, stream>>>(w2, v, p);    // p[0:768]
    k_gemv768<<<dim3(192), dim3(256), 0, stream>>>(w1, p, u);    // u[0:768]
    k_max_score<<<dim3(512), dim3(768), 0, stream>>>(x, ln_w, ln_b, u, t);
    k_gather  <<<dim3(64, 8), dim3(768), 0, stream>>>(inp, t, out);
}